// Round 2
// baseline (3471.521 us; speedup 1.0000x reference)
//
#include <hip/hip_runtime.h>

#define NB 128   // batch
#define NS 128   // context seq len
#define NT 12    // target seq len
#define NE 300   // embed dim
#define NH 512   // hidden
#define NCOL 2048  // 4*NH
#define NBLK 256

typedef _Float16 h8v __attribute__((ext_vector_type(8)));
typedef __attribute__((ext_vector_type(4))) float f4v;
typedef __attribute__((ext_vector_type(4))) int   i4v;

__device__ __forceinline__ unsigned short f2h(float f) {
  union { _Float16 h; unsigned short u; } c; c.h = (_Float16)f; return c.u;
}
__device__ __forceinline__ float sigm(float x) { return 1.f / (1.f + __expf(-x)); }
__device__ __forceinline__ float tanh_(float x) { const float e = __expf(2.f * x); return 1.f - 2.f / (e + 1.f); }

struct Params {
  const int *tids, *tlen, *lids, *llen, *rids, *rlen;
  const float *emb, *Wl, *bl, *Wr, *br, *Wd, *bd;
  float* out;
  unsigned short* hbuf;  // [2(pp)][2(side)][NB][NH] f16 ping-pong
  float* hfin;           // [2(side)][NB][NH] fp32
  int* bar;              // grid barrier counter (zeroed by host memset each launch)
};

// Monotonic-counter grid barrier. Safe because all 256 blocks are co-resident
// (LDS 61.6KB<=64KB, <=512 VGPR -> >=1 block/CU on 256 CUs = grid size).
__device__ __forceinline__ void gsync(int* cnt, int target) {
  __syncthreads();
  if (threadIdx.x == 0) {
    __threadfence();  // publish this block's writes (agent scope)
    __hip_atomic_fetch_add(cnt, 1, __ATOMIC_RELEASE, __HIP_MEMORY_SCOPE_AGENT);
    while (__hip_atomic_load(cnt, __ATOMIC_ACQUIRE, __HIP_MEMORY_SCOPE_AGENT) < target)
      __builtin_amdgcn_s_sleep(1);
    __threadfence();  // acquire other blocks' writes
  }
  __syncthreads();
}

__global__ __launch_bounds__(256, 1) void lstm_all(Params p) {
  // LDS map (61440B main + lenL/redL):
  //  main loop: hS = lds+0     (32 rows x 1024B f16, XOR-swizzled)
  //             xS = lds+32768 (32 rows x 640B  f16, XOR-swizzled)
  //             zS = lds+53248 (32x64 float)
  //  prologue:  meanTT = lds+0 (float[300*32], transposed) -- dead before loop
  //             wT = lds+0     (ushort[64*32])             -- dead before loop
  __shared__ __align__(16) char lds[61440];
  __shared__ int lenL[32];
  __shared__ float redL[16];

  const int tid = threadIdx.x;
  const int wid = blockIdx.x;

  // XCD-friendly mapping: all 32 blocks sharing (side,bt) have equal wid&7
  // -> land on the same XCD (round-robin dispatch), sharing emb/h L2 lines.
  const int bt = wid & 3, side = (wid >> 2) & 1, ht = wid >> 3;
  const int b0 = bt * 32, d0c = ht * 16;
  const int* lenp = side ? p.rlen : p.llen;
  const int* gids = side ? p.rids : p.lids;
  const float* W = side ? p.Wr : p.Wl;
  const float* bias = side ? p.br : p.bl;

  float* meanTT = (float*)lds;
  unsigned short* wT = (unsigned short*)lds;
  float* zS = (float*)(lds + 53248);

  // ---------------- phase 1: mean_t (fp32, transposed [k][r]) ----------------
  {
    const int r = tid >> 3, l8 = tid & 7;
    const int b = b0 + r;
    const int Lt = p.tlen[b];
    const float inv = 1.f / (float)Lt;
    int toks[NT];
    #pragma unroll
    for (int t = 0; t < NT; ++t) toks[t] = p.tids[b * NT + t];
    for (int k = l8; k < NE; k += 8) {
      float s = 0.f;
      #pragma unroll
      for (int t = 0; t < NT; ++t)
        if (t < Lt) s += p.emb[(size_t)toks[t] * NE + k];
      meanTT[k * 32 + r] = s * inv;
    }
    if (tid < 32) lenL[tid] = lenp[b0 + tid];
  }
  __syncthreads();

  // ---------------- phase 2: z_base = bias + mean @ W[300:600] (fp32) ----------------
  const int dloc = tid & 15;
  const int r1 = tid >> 4;   // 0..15
  const int r2 = r1 + 16;
  float zb1[4], zb2[4];
  {
    const int c = tid & 63, rq = tid >> 6;   // col 0..63, row-quarter 0..3
    const int gcol = (c >> 4) * NH + d0c + (c & 15);
    float acc[8];
    #pragma unroll
    for (int i = 0; i < 8; ++i) acc[i] = 0.f;
    const float* wp = W + (size_t)NE * NCOL + gcol;
    for (int k = 0; k < NE; ++k) {
      const float wv = wp[(size_t)k * NCOL];
      const f4v m0 = *(const f4v*)(meanTT + k * 32 + rq * 8);
      const f4v m1 = *(const f4v*)(meanTT + k * 32 + rq * 8 + 4);
      acc[0] += m0[0] * wv; acc[1] += m0[1] * wv; acc[2] += m0[2] * wv; acc[3] += m0[3] * wv;
      acc[4] += m1[0] * wv; acc[5] += m1[1] * wv; acc[6] += m1[2] * wv; acc[7] += m1[3] * wv;
    }
    #pragma unroll
    for (int rr = 0; rr < 8; ++rr) zS[(rq * 8 + rr) * 64 + c] = acc[rr];
  }
  __syncthreads();  // also retires all meanTT reads (wT aliases it)
  #pragma unroll
  for (int g = 0; g < 4; ++g) {
    zb1[g] = zS[r1 * 64 + g * 16 + dloc] + bias[g * NH + d0c + dloc];
    zb2[g] = zS[r2 * 64 + g * 16 + dloc] + bias[g * NH + d0c + dloc];
  }

  // ---------------- phase 3: W -> register B-fragments (f16), via LDS transpose ----------------
  const int wv_ = tid >> 6;
  const int ln  = tid & 63;
  const int mt  = wv_ & 1;          // batch half (16 rows)
  const int gp  = (wv_ >> 1) * 2;   // gate pair {0,1} or {2,3}
  const int kgrp = ln >> 4;
  h8v bfr[2][26];
  {
    const int r3 = tid >> 3, part = tid & 7, s3 = part >> 1, hf = part & 1;
    for (int kt = 0; kt < 26; ++kt) {
      const int k = (kt < 10) ? (kt * 32 + r3) : (600 + (kt - 10) * 32 + r3);
      float v[8];
      if (kt >= 10 || k < NE) {
        const float* wr = W + (size_t)k * NCOL + s3 * NH + d0c + hf * 8;
        const f4v a0 = *(const f4v*)wr;
        const f4v a1 = *(const f4v*)(wr + 4);
        v[0] = a0[0]; v[1] = a0[1]; v[2] = a0[2]; v[3] = a0[3];
        v[4] = a1[0]; v[5] = a1[1]; v[6] = a1[2]; v[7] = a1[3];
      } else {
        #pragma unroll
        for (int j = 0; j < 8; ++j) v[j] = 0.f;
      }
      #pragma unroll
      for (int j = 0; j < 8; ++j)
        wT[(s3 * 16 + hf * 8 + j) * 32 + r3] = f2h(v[j]);   // [localcol][k] transposed
      __syncthreads();
      #pragma unroll
      for (int nt = 0; nt < 2; ++nt) {
        const int cL = (gp + nt) * 16 + (ln & 15);
        bfr[nt][kt] = *(const h8v*)((char*)wT + cL * 64 + kgrp * 16);
      }
      __syncthreads();
    }
  }

  // ---------------- phase 4: zero h ping buffer 0 ----------------
  float cR1 = 0.f, cR2 = 0.f, hR1 = 0.f, hR2 = 0.f;
  {
    unsigned short* bz = p.hbuf + (size_t)side * NB * NH;  // pp = 0
    bz[(size_t)(b0 + r1) * NH + d0c + dloc] = 0;
    bz[(size_t)(b0 + r2) * NH + d0c + dloc] = 0;
  }
  int ep = 0;
  gsync(p.bar, NBLK * (++ep));

  // ---------------- main recurrence: 128 steps ----------------
  int pp = 0;
  const int arow = mt * 16 + (ln & 15);
  for (int t = 0; t < NS; ++t) {
    // stage h: 32 rows x 512 f16 -> LDS (XOR-swizzled, stride 1024B)
    {
      const unsigned short* src = p.hbuf + (size_t)(pp * 2 + side) * NB * NH;
      #pragma unroll
      for (int j = 0; j < 8; ++j) {
        const int idx = j * 256 + tid;
        const int row = idx >> 6, c16 = idx & 63;
        i4v v = *(const i4v*)(src + (size_t)(b0 + row) * NH + c16 * 8);
        *(i4v*)(lds + row * 1024 + ((c16 * 16) ^ ((row & 7) << 4))) = v;
      }
    }
    // gather x: emb[tok] -> f16 LDS (pad 300->320 with zeros; stride 640B)
    {
      const int xrow = tid >> 3;
      const int tok = gids[(size_t)(b0 + xrow) * NS + t];
      const float* ep_ = p.emb + (size_t)tok * NE;
      #pragma unroll
      for (int j = 0; j < 5; ++j) {
        const int c16 = (tid & 7) + j * 8;
        unsigned short tmp[8];
        if (c16 < 37) {
          const f4v v0 = *(const f4v*)(ep_ + c16 * 8);
          const f4v v1 = *(const f4v*)(ep_ + c16 * 8 + 4);
          tmp[0] = f2h(v0[0]); tmp[1] = f2h(v0[1]); tmp[2] = f2h(v0[2]); tmp[3] = f2h(v0[3]);
          tmp[4] = f2h(v1[0]); tmp[5] = f2h(v1[1]); tmp[6] = f2h(v1[2]); tmp[7] = f2h(v1[3]);
        } else if (c16 == 37) {
          const f4v v0 = *(const f4v*)(ep_ + 296);
          tmp[0] = f2h(v0[0]); tmp[1] = f2h(v0[1]); tmp[2] = f2h(v0[2]); tmp[3] = f2h(v0[3]);
          tmp[4] = 0; tmp[5] = 0; tmp[6] = 0; tmp[7] = 0;
        } else {
          #pragma unroll
          for (int q = 0; q < 8; ++q) tmp[q] = 0;
        }
        *(i4v*)(lds + 32768 + xrow * 640 + ((c16 * 16) ^ ((xrow & 7) << 4))) = *(const i4v*)tmp;
      }
    }
    __syncthreads();

    // K-loop: z = x @ W[0:320] + h @ W[600:1112]  (26 kt x 2 N-tiles, f16 MFMA)
    f4v acc0 = {0.f, 0.f, 0.f, 0.f}, acc1 = {0.f, 0.f, 0.f, 0.f};
    #pragma unroll
    for (int kt = 0; kt < 26; ++kt) {
      h8v a;
      if (kt < 10)
        a = *(const h8v*)(lds + 32768 + arow * 640 + (((kt * 4 + kgrp) * 16) ^ ((arow & 7) << 4)));
      else
        a = *(const h8v*)(lds + arow * 1024 + ((((kt - 10) * 4 + kgrp) * 16) ^ ((arow & 7) << 4)));
      acc0 = __builtin_amdgcn_mfma_f32_16x16x32_f16(a, bfr[0][kt], acc0, 0, 0, 0);
      acc1 = __builtin_amdgcn_mfma_f32_16x16x32_f16(a, bfr[1][kt], acc1, 0, 0, 0);
    }
    // D frag: col = lane&15, row = (lane>>4)*4 + rg  (+16*mt)
    #pragma unroll
    for (int rg = 0; rg < 4; ++rg) {
      const int rr = mt * 16 + kgrp * 4 + rg;
      zS[rr * 64 + gp * 16 + (ln & 15)]       = acc0[rg];
      zS[rr * 64 + (gp + 1) * 16 + (ln & 15)] = acc1[rg];
    }
    __syncthreads();

    // elementwise cell update (fp32), write h_new f16 to other ping buffer
    {
      unsigned short* dst = p.hbuf + (size_t)((pp ^ 1) * 2 + side) * NB * NH;
      const float* z1 = zS + r1 * 64 + dloc;
      const float* z2 = zS + r2 * 64 + dloc;
      float zi = z1[0] + zb1[0], zj = z1[16] + zb1[1], zf = z1[32] + zb1[2], zo = z1[48] + zb1[3];
      float ig = sigm(zi), jg = tanh_(zj), fg = sigm(zf + 1.f), og = sigm(zo);
      float cn = fg * cR1 + ig * jg;
      float hn = og * tanh_(cn);
      if (t < lenL[r1]) { cR1 = cn; hR1 = hn; }
      dst[(size_t)(b0 + r1) * NH + d0c + dloc] = f2h(hR1);
      zi = z2[0] + zb2[0]; zj = z2[16] + zb2[1]; zf = z2[32] + zb2[2]; zo = z2[48] + zb2[3];
      ig = sigm(zi); jg = tanh_(zj); fg = sigm(zf + 1.f); og = sigm(zo);
      cn = fg * cR2 + ig * jg; hn = og * tanh_(cn);
      if (t < lenL[r2]) { cR2 = cn; hR2 = hn; }
      dst[(size_t)(b0 + r2) * NH + d0c + dloc] = f2h(hR2);
    }
    pp ^= 1;
    gsync(p.bar, NBLK * (++ep));
  }

  // ---------------- epilogue: final h (fp32) + dense head ----------------
  p.hfin[((size_t)side * NB + b0 + r1) * NH + d0c + dloc] = hR1;
  p.hfin[((size_t)side * NB + b0 + r2) * NH + d0c + dloc] = hR2;
  gsync(p.bar, NBLK * (++ep));

  if (wid < NB) {
    const int b = wid;
    float a0 = 0.f, a1 = 0.f, a2 = 0.f;
    #pragma unroll
    for (int q = 0; q < 4; ++q) {
      const int kk = q * 256 + tid;
      const float hv = (kk < NH) ? p.hfin[(size_t)b * NH + kk]
                                 : p.hfin[((size_t)NB + b) * NH + (kk - NH)];
      a0 += hv * p.Wd[kk * 3 + 0];
      a1 += hv * p.Wd[kk * 3 + 1];
      a2 += hv * p.Wd[kk * 3 + 2];
    }
    #pragma unroll
    for (int s = 32; s > 0; s >>= 1) {
      a0 += __shfl_down(a0, s, 64);
      a1 += __shfl_down(a1, s, 64);
      a2 += __shfl_down(a2, s, 64);
    }
    if (ln == 0) { redL[wv_ * 4 + 0] = a0; redL[wv_ * 4 + 1] = a1; redL[wv_ * 4 + 2] = a2; }
    __syncthreads();
    if (tid == 0) {
      p.out[b * 3 + 0] = redL[0] + redL[4] + redL[8]  + redL[12] + p.bd[0];
      p.out[b * 3 + 1] = redL[1] + redL[5] + redL[9]  + redL[13] + p.bd[1];
      p.out[b * 3 + 2] = redL[2] + redL[6] + redL[10] + redL[14] + p.bd[2];
    }
  }
}

extern "C" void kernel_launch(void* const* d_in, const int* in_sizes, int n_in,
                              void* d_out, int out_size, void* d_ws, size_t ws_size,
                              hipStream_t stream) {
  (void)in_sizes; (void)n_in; (void)out_size; (void)ws_size;
  char* ws = (char*)d_ws;
  Params p;
  p.tids = (const int*)d_in[0];
  p.tlen = (const int*)d_in[1];
  p.lids = (const int*)d_in[2];
  p.llen = (const int*)d_in[3];
  p.rids = (const int*)d_in[4];
  p.rlen = (const int*)d_in[5];
  p.emb  = (const float*)d_in[6];
  p.Wl   = (const float*)d_in[7];
  p.bl   = (const float*)d_in[8];
  p.Wr   = (const float*)d_in[9];
  p.br   = (const float*)d_in[10];
  p.Wd   = (const float*)d_in[11];
  p.bd   = (const float*)d_in[12];
  p.out  = (float*)d_out;
  p.bar  = (int*)ws;                                   // 128 B
  p.hbuf = (unsigned short*)(ws + 128);                // 2*2*128*512*2 = 524,288 B
  p.hfin = (float*)(ws + 128 + 524288);                // 2*128*512*4   = 524,288 B
  hipMemsetAsync(ws, 0, 128, stream);                  // reset barrier counter
  lstm_all<<<dim3(NBLK), dim3(256), 0, stream>>>(p);
}

// Round 3
// 2326.962 us; speedup vs baseline: 1.4919x; 1.4919x over previous
//
#include <hip/hip_runtime.h>

#define NB 128   // batch
#define NS 128   // context seq len
#define NT 12    // target seq len
#define NE 300   // embed dim
#define NH 512   // hidden
#define NCOL 2048  // 4*NH
#define NBLK 256

typedef _Float16 h8v __attribute__((ext_vector_type(8)));
typedef __attribute__((ext_vector_type(4))) float f4v;
typedef __attribute__((ext_vector_type(4))) int   i4v;

__device__ __forceinline__ unsigned short f2h(float f) {
  union { _Float16 h; unsigned short u; } c; c.h = (_Float16)f; return c.u;
}
__device__ __forceinline__ float sigm(float x) { return 1.f / (1.f + __expf(-x)); }
__device__ __forceinline__ float tanh_(float x) { const float e = __expf(2.f * x); return 1.f - 2.f / (e + 1.f); }

struct Params {
  const int *tids, *tlen, *lids, *llen, *rids, *rlen;
  const float *emb, *Wl, *bl, *Wr, *br, *Wd, *bd;
  float* out;
  unsigned short* hbuf;  // [2(pp)][2(side)][NB][NH] f16 ping-pong
  float* hfin;           // [2(side)][NB][NH] fp32
  int* bar;              // flags: [8 groups][32 slots] int, 128B/group line
};

// ---- per-group barrier (group = 32 blocks sharing (side,bt)) ----
// Block publishes "epoch" into its slot (release, agent scope: waitcnt+wbL2+store).
// Waiters poll the 32-slot line with relaxed agent loads (sc-bits -> read past
// stale L2), then acquire-fence (invL1/L2) before reading peer h data.
// Correct regardless of block->XCD placement; fast when group is co-XCD.
__device__ __forceinline__ void group_release(int* fl, int slot, int val) {
  __syncthreads();  // drains all waves' vm stores (compiler emits vmcnt(0) before s_barrier)
  if (threadIdx.x == 0)
    __hip_atomic_store(fl + slot, val, __ATOMIC_RELEASE, __HIP_MEMORY_SCOPE_AGENT);
}
__device__ __forceinline__ void group_wait(const int* fl, int target) {
  if (threadIdx.x < 64) {
    const int* f = fl + (threadIdx.x & 31);
    int v = __hip_atomic_load(f, __ATOMIC_RELAXED, __HIP_MEMORY_SCOPE_AGENT);
    while (__ballot(v < target) != 0ull) {
      __builtin_amdgcn_s_sleep(1);
      v = __hip_atomic_load(f, __ATOMIC_RELAXED, __HIP_MEMORY_SCOPE_AGENT);
    }
  }
  __syncthreads();
  __builtin_amdgcn_fence(__ATOMIC_ACQUIRE, "agent");
}

__global__ __launch_bounds__(256, 1) void lstm_all(Params p) {
  // LDS map (61440B main):
  //  loop:     hS = lds+0     (32 rows x 1024B f16, XOR-swizzled)
  //            xS = lds+32768 (32 rows x 640B  f16, XOR-swizzled)
  //            zS = lds+53248 (32x64 float)
  //  prologue: meanTT = lds+0 (float[300*32], transposed) -- dead before loop
  //            wT = lds+0     (ushort[64*32])             -- dead before loop
  __shared__ __align__(16) char lds[61440];
  __shared__ int lenL[32];
  __shared__ float redL[16];

  const int tid = threadIdx.x;
  const int wid = blockIdx.x;

  // all 32 blocks sharing (side,bt) have equal wid&7 -> same XCD under
  // round-robin dispatch (locality heuristic only, not correctness)
  const int bt = wid & 3, side = (wid >> 2) & 1, ht = wid >> 3;
  const int b0 = bt * 32, d0c = ht * 16;
  const int* lenp = side ? p.rlen : p.llen;
  const int* gids = side ? p.rids : p.lids;
  const float* W = side ? p.Wr : p.Wl;
  const float* bias = side ? p.br : p.bl;
  int* fl = p.bar + (side * 4 + bt) * 32;

  float* meanTT = (float*)lds;
  unsigned short* wT = (unsigned short*)lds;
  float* zS = (float*)(lds + 53248);

  // ---------------- phase 1: mean_t (fp32, transposed [k][r]) ----------------
  {
    const int r = tid >> 3, l8 = tid & 7;
    const int b = b0 + r;
    const int Lt = p.tlen[b];
    const float inv = 1.f / (float)Lt;
    int toks[NT];
    #pragma unroll
    for (int t = 0; t < NT; ++t) toks[t] = p.tids[b * NT + t];
    for (int k = l8; k < NE; k += 8) {
      float s = 0.f;
      #pragma unroll
      for (int t = 0; t < NT; ++t)
        if (t < Lt) s += p.emb[(size_t)toks[t] * NE + k];
      meanTT[k * 32 + r] = s * inv;
    }
    if (tid < 32) lenL[tid] = lenp[b0 + tid];
  }
  __syncthreads();

  // ---------------- phase 2: z_base = bias + mean @ W[300:600] (fp32) ----------------
  const int dloc = tid & 15;
  const int r1 = tid >> 4;   // 0..15
  const int r2 = r1 + 16;
  float zb1[4], zb2[4];
  {
    const int c = tid & 63, rq = tid >> 6;   // col 0..63, row-quarter 0..3
    const int gcol = (c >> 4) * NH + d0c + (c & 15);
    float acc[8];
    #pragma unroll
    for (int i = 0; i < 8; ++i) acc[i] = 0.f;
    const float* wp = W + (size_t)NE * NCOL + gcol;
    for (int k = 0; k < NE; ++k) {
      const float wv = wp[(size_t)k * NCOL];
      const f4v m0 = *(const f4v*)(meanTT + k * 32 + rq * 8);
      const f4v m1 = *(const f4v*)(meanTT + k * 32 + rq * 8 + 4);
      acc[0] += m0[0] * wv; acc[1] += m0[1] * wv; acc[2] += m0[2] * wv; acc[3] += m0[3] * wv;
      acc[4] += m1[0] * wv; acc[5] += m1[1] * wv; acc[6] += m1[2] * wv; acc[7] += m1[3] * wv;
    }
    #pragma unroll
    for (int rr = 0; rr < 8; ++rr) zS[(rq * 8 + rr) * 64 + c] = acc[rr];
  }
  __syncthreads();  // also retires all meanTT reads (wT aliases it)
  #pragma unroll
  for (int g = 0; g < 4; ++g) {
    zb1[g] = zS[r1 * 64 + g * 16 + dloc] + bias[g * NH + d0c + dloc];
    zb2[g] = zS[r2 * 64 + g * 16 + dloc] + bias[g * NH + d0c + dloc];
  }
  __syncthreads();

  // ---------------- phase 3: W -> register B-fragments (f16), via LDS transpose ----------------
  const int wv_ = tid >> 6;
  const int ln  = tid & 63;
  const int mt  = wv_ & 1;          // batch half (16 rows)
  const int gp  = (wv_ >> 1) * 2;   // gate pair {0,1} or {2,3}
  const int kgrp = ln >> 4;
  h8v bfr[2][26];
  {
    const int r3 = tid >> 3, part = tid & 7, s3 = part >> 1, hf = part & 1;
    for (int kt = 0; kt < 26; ++kt) {
      const int k = (kt < 10) ? (kt * 32 + r3) : (600 + (kt - 10) * 32 + r3);
      float v[8];
      if (kt >= 10 || k < NE) {
        const float* wr = W + (size_t)k * NCOL + s3 * NH + d0c + hf * 8;
        const f4v a0 = *(const f4v*)wr;
        const f4v a1 = *(const f4v*)(wr + 4);
        v[0] = a0[0]; v[1] = a0[1]; v[2] = a0[2]; v[3] = a0[3];
        v[4] = a1[0]; v[5] = a1[1]; v[6] = a1[2]; v[7] = a1[3];
      } else {
        #pragma unroll
        for (int j = 0; j < 8; ++j) v[j] = 0.f;
      }
      #pragma unroll
      for (int j = 0; j < 8; ++j)
        wT[(s3 * 16 + hf * 8 + j) * 32 + r3] = f2h(v[j]);   // [localcol][k] transposed
      __syncthreads();
      #pragma unroll
      for (int nt = 0; nt < 2; ++nt) {
        const int cL = (gp + nt) * 16 + (ln & 15);
        bfr[nt][kt] = *(const h8v*)((char*)wT + cL * 64 + kgrp * 16);
      }
      __syncthreads();
    }
  }

  // ---------------- x-gather helper (emb[tok] -> f16 LDS, pad 300->320) ----------------
  auto gather_x = [&](int t) {
    const int xrow = tid >> 3;
    const int tok = gids[(size_t)(b0 + xrow) * NS + t];
    const float* ep_ = p.emb + (size_t)tok * NE;
    #pragma unroll
    for (int j = 0; j < 5; ++j) {
      const int c16 = (tid & 7) + j * 8;
      unsigned short tmp[8];
      if (c16 < 37) {
        const f4v v0 = *(const f4v*)(ep_ + c16 * 8);
        const f4v v1 = *(const f4v*)(ep_ + c16 * 8 + 4);
        tmp[0] = f2h(v0[0]); tmp[1] = f2h(v0[1]); tmp[2] = f2h(v0[2]); tmp[3] = f2h(v0[3]);
        tmp[4] = f2h(v1[0]); tmp[5] = f2h(v1[1]); tmp[6] = f2h(v1[2]); tmp[7] = f2h(v1[3]);
      } else if (c16 == 37) {
        const f4v v0 = *(const f4v*)(ep_ + 296);
        tmp[0] = f2h(v0[0]); tmp[1] = f2h(v0[1]); tmp[2] = f2h(v0[2]); tmp[3] = f2h(v0[3]);
        tmp[4] = 0; tmp[5] = 0; tmp[6] = 0; tmp[7] = 0;
      } else {
        #pragma unroll
        for (int q = 0; q < 8; ++q) tmp[q] = 0;
      }
      *(i4v*)(lds + 32768 + xrow * 640 + ((c16 * 16) ^ ((xrow & 7) << 4))) = *(const i4v*)tmp;
    }
  };

  // prime x_0 (no cross-block dependency); h_0 is zeroed in LDS at t==0
  gather_x(0);

  // ---------------- main recurrence: 128 steps ----------------
  float cR1 = 0.f, cR2 = 0.f, hR1 = 0.f, hR2 = 0.f;
  int pp = 0;
  const int arow = mt * 16 + (ln & 15);
  for (int t = 0; t < NS; ++t) {
    if (t == 0) {
      // zero hS (h_0 = 0), no global exchange needed
      #pragma unroll
      for (int j = 0; j < 8; ++j) {
        const i4v z = {0, 0, 0, 0};
        *(i4v*)(lds + (j * 256 + tid) * 16) = z;
      }
    } else {
      // stage h_t: 32 rows x 512 f16 -> LDS (XOR-swizzled, stride 1024B)
      const unsigned short* src = p.hbuf + (size_t)(pp * 2 + side) * NB * NH;
      #pragma unroll
      for (int j = 0; j < 8; ++j) {
        const int idx = j * 256 + tid;
        const int row = idx >> 6, c16 = idx & 63;
        i4v v = *(const i4v*)(src + (size_t)(b0 + row) * NH + c16 * 8);
        *(i4v*)(lds + row * 1024 + ((c16 * 16) ^ ((row & 7) << 4))) = v;
      }
    }
    __syncthreads();

    // K-loop: z = x @ W[0:320] + h @ W[600:1112]  (26 kt x 2 N-tiles, f16 MFMA)
    f4v acc0 = {0.f, 0.f, 0.f, 0.f}, acc1 = {0.f, 0.f, 0.f, 0.f};
    #pragma unroll
    for (int kt = 0; kt < 26; ++kt) {
      h8v a;
      if (kt < 10)
        a = *(const h8v*)(lds + 32768 + arow * 640 + (((kt * 4 + kgrp) * 16) ^ ((arow & 7) << 4)));
      else
        a = *(const h8v*)(lds + arow * 1024 + ((((kt - 10) * 4 + kgrp) * 16) ^ ((arow & 7) << 4)));
      acc0 = __builtin_amdgcn_mfma_f32_16x16x32_f16(a, bfr[0][kt], acc0, 0, 0, 0);
      acc1 = __builtin_amdgcn_mfma_f32_16x16x32_f16(a, bfr[1][kt], acc1, 0, 0, 0);
    }
    // D frag: col = lane&15, row = (lane>>4)*4 + rg  (+16*mt)
    #pragma unroll
    for (int rg = 0; rg < 4; ++rg) {
      const int rr = mt * 16 + kgrp * 4 + rg;
      zS[rr * 64 + gp * 16 + (ln & 15)]       = acc0[rg];
      zS[rr * 64 + (gp + 1) * 16 + (ln & 15)] = acc1[rg];
    }
    __syncthreads();

    // elementwise cell update (fp32), write h_{t+1} f16 to other ping buffer
    {
      unsigned short* dst = p.hbuf + (size_t)((pp ^ 1) * 2 + side) * NB * NH;
      const float* z1 = zS + r1 * 64 + dloc;
      const float* z2 = zS + r2 * 64 + dloc;
      float zi = z1[0] + zb1[0], zj = z1[16] + zb1[1], zf = z1[32] + zb1[2], zo = z1[48] + zb1[3];
      float ig = sigm(zi), jg = tanh_(zj), fg = sigm(zf + 1.f), og = sigm(zo);
      float cn = fg * cR1 + ig * jg;
      float hn = og * tanh_(cn);
      if (t < lenL[r1]) { cR1 = cn; hR1 = hn; }
      dst[(size_t)(b0 + r1) * NH + d0c + dloc] = f2h(hR1);
      zi = z2[0] + zb2[0]; zj = z2[16] + zb2[1]; zf = z2[32] + zb2[2]; zo = z2[48] + zb2[3];
      ig = sigm(zi); jg = tanh_(zj); fg = sigm(zf + 1.f); og = sigm(zo);
      cn = fg * cR2 + ig * jg; hn = og * tanh_(cn);
      if (t < lenL[r2]) { cR2 = cn; hR2 = hn; }
      dst[(size_t)(b0 + r2) * NH + d0c + dloc] = f2h(hR2);
    }

    // publish h_{t+1}; overlap next-x gather with peers' progress; then wait
    group_release(fl, ht, t + 1);
    if (t < NS - 1) gather_x(t + 1);
    group_wait(fl, t + 1);
    pp ^= 1;
  }

  // ---------------- epilogue: final h (fp32) + dense head ----------------
  p.hfin[((size_t)side * NB + b0 + r1) * NH + d0c + dloc] = hR1;
  p.hfin[((size_t)side * NB + b0 + r2) * NH + d0c + dloc] = hR2;
  group_release(fl, ht, NS + 1);   // flag 129: hfin ready

  if (wid < NB) {
    const int b = wid, btq = b >> 5;
    // wait for both sides' groups covering batch-tile btq
    if (tid < 64) {
      const int gsel = tid >> 5;   // 0: side0 group, 1: side1 group
      const int* f = p.bar + (gsel * 4 + btq) * 32 + (tid & 31);
      int v = __hip_atomic_load(f, __ATOMIC_RELAXED, __HIP_MEMORY_SCOPE_AGENT);
      while (__ballot(v < NS + 1) != 0ull) {
        __builtin_amdgcn_s_sleep(1);
        v = __hip_atomic_load(f, __ATOMIC_RELAXED, __HIP_MEMORY_SCOPE_AGENT);
      }
    }
    __syncthreads();
    __builtin_amdgcn_fence(__ATOMIC_ACQUIRE, "agent");

    float a0 = 0.f, a1 = 0.f, a2 = 0.f;
    #pragma unroll
    for (int q = 0; q < 4; ++q) {
      const int kk = q * 256 + tid;
      const float hv = (kk < NH) ? p.hfin[(size_t)b * NH + kk]
                                 : p.hfin[((size_t)NB + b) * NH + (kk - NH)];
      a0 += hv * p.Wd[kk * 3 + 0];
      a1 += hv * p.Wd[kk * 3 + 1];
      a2 += hv * p.Wd[kk * 3 + 2];
    }
    #pragma unroll
    for (int s = 32; s > 0; s >>= 1) {
      a0 += __shfl_down(a0, s, 64);
      a1 += __shfl_down(a1, s, 64);
      a2 += __shfl_down(a2, s, 64);
    }
    if (ln == 0) { redL[wv_ * 4 + 0] = a0; redL[wv_ * 4 + 1] = a1; redL[wv_ * 4 + 2] = a2; }
    __syncthreads();
    if (tid == 0) {
      p.out[b * 3 + 0] = redL[0] + redL[4] + redL[8]  + redL[12] + p.bd[0];
      p.out[b * 3 + 1] = redL[1] + redL[5] + redL[9]  + redL[13] + p.bd[1];
      p.out[b * 3 + 2] = redL[2] + redL[6] + redL[10] + redL[14] + p.bd[2];
    }
  }
}

extern "C" void kernel_launch(void* const* d_in, const int* in_sizes, int n_in,
                              void* d_out, int out_size, void* d_ws, size_t ws_size,
                              hipStream_t stream) {
  (void)in_sizes; (void)n_in; (void)out_size; (void)ws_size;
  char* ws = (char*)d_ws;
  Params p;
  p.tids = (const int*)d_in[0];
  p.tlen = (const int*)d_in[1];
  p.lids = (const int*)d_in[2];
  p.llen = (const int*)d_in[3];
  p.rids = (const int*)d_in[4];
  p.rlen = (const int*)d_in[5];
  p.emb  = (const float*)d_in[6];
  p.Wl   = (const float*)d_in[7];
  p.bl   = (const float*)d_in[8];
  p.Wr   = (const float*)d_in[9];
  p.br   = (const float*)d_in[10];
  p.Wd   = (const float*)d_in[11];
  p.bd   = (const float*)d_in[12];
  p.out  = (float*)d_out;
  p.bar  = (int*)ws;                                   // 8 groups x 32 int = 1024 B
  p.hbuf = (unsigned short*)(ws + 1024);               // 2*2*128*512*2 = 524,288 B
  p.hfin = (float*)(ws + 1024 + 524288);               // 2*128*512*4   = 524,288 B
  hipMemsetAsync(ws, 0, 1024, stream);                 // reset flags each launch
  lstm_all<<<dim3(NBLK), dim3(256), 0, stream>>>(p);
}

// Round 4
// 811.149 us; speedup vs baseline: 4.2798x; 2.8687x over previous
//
#include <hip/hip_runtime.h>

#define NB 128   // batch
#define NS 128   // context seq len
#define NT 12    // target seq len
#define NE 300   // embed dim
#define NH 512   // hidden
#define NCOL 2048  // 4*NH
#define NBLK 256

typedef _Float16 h8v __attribute__((ext_vector_type(8)));
typedef __attribute__((ext_vector_type(4))) float f4v;
typedef __attribute__((ext_vector_type(4))) int   i4v;

__device__ __forceinline__ unsigned short f2h(float f) {
  union { _Float16 h; unsigned short u; } c; c.h = (_Float16)f; return c.u;
}
__device__ __forceinline__ float sigm(float x) { return 1.f / (1.f + __expf(-x)); }
__device__ __forceinline__ float tanh_(float x) { const float e = __expf(2.f * x); return 1.f - 2.f / (e + 1.f); }

// ---- device-scope UNCACHED accesses (sc1: bypass L1/L2, coherence at IF) ----
// These make cross-XCD data exchange work with NO buffer_wbl2 / buffer_inv.
__device__ __forceinline__ void st16_uc(unsigned short* p, unsigned short v) {
  unsigned vv = v;
  asm volatile("global_store_short %0, %1, off sc1" :: "v"(p), "v"(vv) : "memory");
}
__device__ __forceinline__ void st32_uc(float* p, float v) {
  asm volatile("global_store_dword %0, %1, off sc1" :: "v"(p), "v"(v) : "memory");
}
// batched 8x16B uncached loads (stride 4096B), single waitcnt at the end
__device__ __forceinline__ void ld8_uc(const unsigned short* base, i4v* r) {
  const char* a = (const char*)base;
  asm volatile(
    "global_load_dwordx4 %0, %8, off sc1\n\t"
    "global_load_dwordx4 %1, %9, off sc1\n\t"
    "global_load_dwordx4 %2, %10, off sc1\n\t"
    "global_load_dwordx4 %3, %11, off sc1\n\t"
    "global_load_dwordx4 %4, %12, off sc1\n\t"
    "global_load_dwordx4 %5, %13, off sc1\n\t"
    "global_load_dwordx4 %6, %14, off sc1\n\t"
    "global_load_dwordx4 %7, %15, off sc1\n\t"
    "s_waitcnt vmcnt(0)"
    : "=&v"(r[0]), "=&v"(r[1]), "=&v"(r[2]), "=&v"(r[3]),
      "=&v"(r[4]), "=&v"(r[5]), "=&v"(r[6]), "=&v"(r[7])
    : "v"(a), "v"(a + 4096), "v"(a + 8192), "v"(a + 12288),
      "v"(a + 16384), "v"(a + 20480), "v"(a + 24576), "v"(a + 28672)
    : "memory");
}

struct Params {
  const int *tids, *tlen, *lids, *llen, *rids, *rlen;
  const float *emb, *Wl, *bl, *Wr, *br, *Wd, *bd;
  float* out;
  unsigned short* hbuf;  // [2(pp)][2(side)][NB][NH] f16 ping-pong (uncached access)
  float* hfin;           // [2(side)][NB][NH] fp32 (uncached access)
  int* bar;              // flags: [8 groups][32 slots] int, 128B/group line
};

// ---- per-group barrier (group = 32 blocks sharing (side,bt)) ----
// All exchanged data uses sc1 (uncached) ops, so NO cache maintenance needed:
// release = drain own stores (vmcnt) in every wave + relaxed flag store;
// wait = poll flags (relaxed agent = sc1 loads) + block barrier. No fences.
__device__ __forceinline__ void group_release(int* fl, int slot, int val) {
  asm volatile("s_waitcnt vmcnt(0)" ::: "memory");  // every wave drains its uncached stores
  __syncthreads();
  if (threadIdx.x == 0)
    __hip_atomic_store(fl + slot, val, __ATOMIC_RELAXED, __HIP_MEMORY_SCOPE_AGENT);
}
__device__ __forceinline__ void group_wait(const int* fl, int target) {
  if (threadIdx.x < 64) {
    const int* f = fl + (threadIdx.x & 31);
    int v = __hip_atomic_load(f, __ATOMIC_RELAXED, __HIP_MEMORY_SCOPE_AGENT);
    while (__ballot(v < target) != 0ull) {
      __builtin_amdgcn_s_sleep(1);
      v = __hip_atomic_load(f, __ATOMIC_RELAXED, __HIP_MEMORY_SCOPE_AGENT);
    }
  }
  __syncthreads();
}

__global__ __launch_bounds__(256, 1) void lstm_all(Params p) {
  // LDS map (61440B main):
  //  loop:     hS = lds+0     (32 rows x 1024B f16, XOR-swizzled)
  //            xS = lds+32768 (32 rows x 640B  f16, XOR-swizzled)
  //            zS = lds+53248 (32x64 float)
  //  prologue: meanTT = lds+0 (float[300*32], transposed) -- dead before loop
  //            wT = lds+0     (ushort[64*32])             -- dead before loop
  __shared__ __align__(16) char lds[61440];
  __shared__ int lenL[32];
  __shared__ float redL[16];

  const int tid = threadIdx.x;
  const int wid = blockIdx.x;

  // all 32 blocks sharing (side,bt) have equal wid&7 -> same XCD under
  // round-robin dispatch (locality heuristic only, not correctness)
  const int bt = wid & 3, side = (wid >> 2) & 1, ht = wid >> 3;
  const int b0 = bt * 32, d0c = ht * 16;
  const int* lenp = side ? p.rlen : p.llen;
  const int* gids = side ? p.rids : p.lids;
  const float* W = side ? p.Wr : p.Wl;
  const float* bias = side ? p.br : p.bl;
  int* fl = p.bar + (side * 4 + bt) * 32;

  float* meanTT = (float*)lds;
  unsigned short* wT = (unsigned short*)lds;
  float* zS = (float*)(lds + 53248);

  // ---------------- phase 1: mean_t (fp32, transposed [k][r]) ----------------
  {
    const int r = tid >> 3, l8 = tid & 7;
    const int b = b0 + r;
    const int Lt = p.tlen[b];
    const float inv = 1.f / (float)Lt;
    int toks[NT];
    #pragma unroll
    for (int t = 0; t < NT; ++t) toks[t] = p.tids[b * NT + t];
    for (int k = l8; k < NE; k += 8) {
      float s = 0.f;
      #pragma unroll
      for (int t = 0; t < NT; ++t)
        if (t < Lt) s += p.emb[(size_t)toks[t] * NE + k];
      meanTT[k * 32 + r] = s * inv;
    }
    if (tid < 32) lenL[tid] = lenp[b0 + tid];
  }
  __syncthreads();

  // ---------------- phase 2: z_base = bias + mean @ W[300:600] (fp32) ----------------
  const int dloc = tid & 15;
  const int r1 = tid >> 4;   // 0..15
  const int r2 = r1 + 16;
  float zb1[4], zb2[4];
  {
    const int c = tid & 63, rq = tid >> 6;   // col 0..63, row-quarter 0..3
    const int gcol = (c >> 4) * NH + d0c + (c & 15);
    float acc[8];
    #pragma unroll
    for (int i = 0; i < 8; ++i) acc[i] = 0.f;
    const float* wp = W + (size_t)NE * NCOL + gcol;
    for (int k = 0; k < NE; ++k) {
      const float wv = wp[(size_t)k * NCOL];
      const f4v m0 = *(const f4v*)(meanTT + k * 32 + rq * 8);
      const f4v m1 = *(const f4v*)(meanTT + k * 32 + rq * 8 + 4);
      acc[0] += m0[0] * wv; acc[1] += m0[1] * wv; acc[2] += m0[2] * wv; acc[3] += m0[3] * wv;
      acc[4] += m1[0] * wv; acc[5] += m1[1] * wv; acc[6] += m1[2] * wv; acc[7] += m1[3] * wv;
    }
    #pragma unroll
    for (int rr = 0; rr < 8; ++rr) zS[(rq * 8 + rr) * 64 + c] = acc[rr];
  }
  __syncthreads();  // also retires all meanTT reads (wT aliases it)
  #pragma unroll
  for (int g = 0; g < 4; ++g) {
    zb1[g] = zS[r1 * 64 + g * 16 + dloc] + bias[g * NH + d0c + dloc];
    zb2[g] = zS[r2 * 64 + g * 16 + dloc] + bias[g * NH + d0c + dloc];
  }
  __syncthreads();

  // ---------------- phase 3: W -> register B-fragments (f16), via LDS transpose ----------------
  const int wv_ = tid >> 6;
  const int ln  = tid & 63;
  const int mt  = wv_ & 1;          // batch half (16 rows)
  const int gp  = (wv_ >> 1) * 2;   // gate pair {0,1} or {2,3}
  const int kgrp = ln >> 4;
  h8v bfr[2][26];
  {
    const int r3 = tid >> 3, part = tid & 7, s3 = part >> 1, hf = part & 1;
    for (int kt = 0; kt < 26; ++kt) {
      const int k = (kt < 10) ? (kt * 32 + r3) : (600 + (kt - 10) * 32 + r3);
      float v[8];
      if (kt >= 10 || k < NE) {
        const float* wr = W + (size_t)k * NCOL + s3 * NH + d0c + hf * 8;
        const f4v a0 = *(const f4v*)wr;
        const f4v a1 = *(const f4v*)(wr + 4);
        v[0] = a0[0]; v[1] = a0[1]; v[2] = a0[2]; v[3] = a0[3];
        v[4] = a1[0]; v[5] = a1[1]; v[6] = a1[2]; v[7] = a1[3];
      } else {
        #pragma unroll
        for (int j = 0; j < 8; ++j) v[j] = 0.f;
      }
      #pragma unroll
      for (int j = 0; j < 8; ++j)
        wT[(s3 * 16 + hf * 8 + j) * 32 + r3] = f2h(v[j]);   // [localcol][k] transposed
      __syncthreads();
      #pragma unroll
      for (int nt = 0; nt < 2; ++nt) {
        const int cL = (gp + nt) * 16 + (ln & 15);
        bfr[nt][kt] = *(const h8v*)((char*)wT + cL * 64 + kgrp * 16);
      }
      __syncthreads();
    }
  }

  // ---------------- x-gather helper (emb[tok] -> f16 LDS, pad 300->320) ----------------
  auto gather_x = [&](int t) {
    const int xrow = tid >> 3;
    const int tok = gids[(size_t)(b0 + xrow) * NS + t];
    const float* ep_ = p.emb + (size_t)tok * NE;
    #pragma unroll
    for (int j = 0; j < 5; ++j) {
      const int c16 = (tid & 7) + j * 8;
      unsigned short tmp[8];
      if (c16 < 37) {
        const f4v v0 = *(const f4v*)(ep_ + c16 * 8);
        const f4v v1 = *(const f4v*)(ep_ + c16 * 8 + 4);
        tmp[0] = f2h(v0[0]); tmp[1] = f2h(v0[1]); tmp[2] = f2h(v0[2]); tmp[3] = f2h(v0[3]);
        tmp[4] = f2h(v1[0]); tmp[5] = f2h(v1[1]); tmp[6] = f2h(v1[2]); tmp[7] = f2h(v1[3]);
      } else if (c16 == 37) {
        const f4v v0 = *(const f4v*)(ep_ + 296);
        tmp[0] = f2h(v0[0]); tmp[1] = f2h(v0[1]); tmp[2] = f2h(v0[2]); tmp[3] = f2h(v0[3]);
        tmp[4] = 0; tmp[5] = 0; tmp[6] = 0; tmp[7] = 0;
      } else {
        #pragma unroll
        for (int q = 0; q < 8; ++q) tmp[q] = 0;
      }
      *(i4v*)(lds + 32768 + xrow * 640 + ((c16 * 16) ^ ((xrow & 7) << 4))) = *(const i4v*)tmp;
    }
  };

  const int arow = mt * 16 + (ln & 15);
  f4v acc0, acc1;
  auto xmfma = [&]() {   // 10 kt x 2 N-tiles: z += x @ W[0:320]
    #pragma unroll
    for (int kt = 0; kt < 10; ++kt) {
      h8v a = *(const h8v*)(lds + 32768 + arow * 640 + (((kt * 4 + kgrp) * 16) ^ ((arow & 7) << 4)));
      acc0 = __builtin_amdgcn_mfma_f32_16x16x32_f16(a, bfr[0][kt], acc0, 0, 0, 0);
      acc1 = __builtin_amdgcn_mfma_f32_16x16x32_f16(a, bfr[1][kt], acc1, 0, 0, 0);
    }
  };

  // prime step 0: x_0 gather + x-MFMA (h_0 = 0 -> no h contribution)
  gather_x(0);
  __syncthreads();
  acc0 = f4v{0.f, 0.f, 0.f, 0.f}; acc1 = f4v{0.f, 0.f, 0.f, 0.f};
  xmfma();

  // ---------------- main recurrence: 128 steps ----------------
  float cR1 = 0.f, cR2 = 0.f, hR1 = 0.f, hR2 = 0.f;
  for (int t = 0; t < NS; ++t) {
    if (t) {
      // wait for peers' h_t, then stage it (uncached 16B loads -> swizzled LDS)
      group_wait(fl, t);
      const unsigned short* src =
          p.hbuf + (size_t)(((t & 1) * 2 + side) * NB + b0 + wv_) * NH + ln * 8;
      i4v hv[8];
      ld8_uc(src, hv);
      #pragma unroll
      for (int j = 0; j < 8; ++j) {
        const int row = j * 4 + wv_;
        *(i4v*)(lds + row * 1024 + ((ln * 16) ^ ((row & 7) << 4))) = hv[j];
      }
      __syncthreads();
      #pragma unroll
      for (int kt = 10; kt < 26; ++kt) {   // z += h @ W[600:1112]
        h8v a = *(const h8v*)(lds + arow * 1024 + ((((kt - 10) * 4 + kgrp) * 16) ^ ((arow & 7) << 4)));
        acc0 = __builtin_amdgcn_mfma_f32_16x16x32_f16(a, bfr[0][kt], acc0, 0, 0, 0);
        acc1 = __builtin_amdgcn_mfma_f32_16x16x32_f16(a, bfr[1][kt], acc1, 0, 0, 0);
      }
    }
    // D frag: col = lane&15, row = (lane>>4)*4 + rg  (+16*mt)
    #pragma unroll
    for (int rg = 0; rg < 4; ++rg) {
      const int rr = mt * 16 + kgrp * 4 + rg;
      zS[rr * 64 + gp * 16 + (ln & 15)]       = acc0[rg];
      zS[rr * 64 + (gp + 1) * 16 + (ln & 15)] = acc1[rg];
    }
    __syncthreads();

    // elementwise cell update (fp32); h_{t+1} via uncached stores
    {
      unsigned short* dst = p.hbuf + (size_t)(((t + 1) & 1) * 2 + side) * NB * NH;
      const float* z1 = zS + r1 * 64 + dloc;
      const float* z2 = zS + r2 * 64 + dloc;
      float zi = z1[0] + zb1[0], zj = z1[16] + zb1[1], zf = z1[32] + zb1[2], zo = z1[48] + zb1[3];
      float ig = sigm(zi), jg = tanh_(zj), fg = sigm(zf + 1.f), og = sigm(zo);
      float cn = fg * cR1 + ig * jg;
      float hn = og * tanh_(cn);
      if (t < lenL[r1]) { cR1 = cn; hR1 = hn; }
      st16_uc(&dst[(size_t)(b0 + r1) * NH + d0c + dloc], f2h(hR1));
      zi = z2[0] + zb2[0]; zj = z2[16] + zb2[1]; zf = z2[32] + zb2[2]; zo = z2[48] + zb2[3];
      ig = sigm(zi); jg = tanh_(zj); fg = sigm(zf + 1.f); og = sigm(zo);
      cn = fg * cR2 + ig * jg; hn = og * tanh_(cn);
      if (t < lenL[r2]) { cR2 = cn; hR2 = hn; }
      st16_uc(&dst[(size_t)(b0 + r2) * NH + d0c + dloc], f2h(hR2));
    }

    // publish h_{t+1}; then prep x(t+1) and its MFMAs before waiting (off critical path)
    group_release(fl, ht, t + 1);
    if (t < NS - 1) {
      gather_x(t + 1);
      __syncthreads();
      acc0 = f4v{0.f, 0.f, 0.f, 0.f}; acc1 = f4v{0.f, 0.f, 0.f, 0.f};
      xmfma();
    }
  }

  // ---------------- epilogue: final h (uncached fp32) + dense head ----------------
  st32_uc(&p.hfin[((size_t)side * NB + b0 + r1) * NH + d0c + dloc], hR1);
  st32_uc(&p.hfin[((size_t)side * NB + b0 + r2) * NH + d0c + dloc], hR2);
  group_release(fl, ht, NS + 1);   // flag 129: hfin ready

  if (wid < NB) {
    const int b = wid, btq = b >> 5;
    // wait for both sides' groups covering batch-tile btq
    if (tid < 64) {
      const int gsel = tid >> 5;   // 0: side0 group, 1: side1 group
      const int* f = p.bar + (gsel * 4 + btq) * 32 + (tid & 31);
      int v = __hip_atomic_load(f, __ATOMIC_RELAXED, __HIP_MEMORY_SCOPE_AGENT);
      while (__ballot(v < NS + 1) != 0ull) {
        __builtin_amdgcn_s_sleep(1);
        v = __hip_atomic_load(f, __ATOMIC_RELAXED, __HIP_MEMORY_SCOPE_AGENT);
      }
    }
    __syncthreads();

    float a0 = 0.f, a1 = 0.f, a2 = 0.f;
    #pragma unroll
    for (int q = 0; q < 4; ++q) {
      const int kk = q * 256 + tid;
      const float* hp = (kk < NH) ? &p.hfin[(size_t)b * NH + kk]
                                  : &p.hfin[((size_t)NB + b) * NH + (kk - NH)];
      const float hv = __hip_atomic_load(hp, __ATOMIC_RELAXED, __HIP_MEMORY_SCOPE_AGENT);
      a0 += hv * p.Wd[kk * 3 + 0];
      a1 += hv * p.Wd[kk * 3 + 1];
      a2 += hv * p.Wd[kk * 3 + 2];
    }
    #pragma unroll
    for (int s = 32; s > 0; s >>= 1) {
      a0 += __shfl_down(a0, s, 64);
      a1 += __shfl_down(a1, s, 64);
      a2 += __shfl_down(a2, s, 64);
    }
    if (ln == 0) { redL[wv_ * 4 + 0] = a0; redL[wv_ * 4 + 1] = a1; redL[wv_ * 4 + 2] = a2; }
    __syncthreads();
    if (tid == 0) {
      p.out[b * 3 + 0] = redL[0] + redL[4] + redL[8]  + redL[12] + p.bd[0];
      p.out[b * 3 + 1] = redL[1] + redL[5] + redL[9]  + redL[13] + p.bd[1];
      p.out[b * 3 + 2] = redL[2] + redL[6] + redL[10] + redL[14] + p.bd[2];
    }
  }
}

extern "C" void kernel_launch(void* const* d_in, const int* in_sizes, int n_in,
                              void* d_out, int out_size, void* d_ws, size_t ws_size,
                              hipStream_t stream) {
  (void)in_sizes; (void)n_in; (void)out_size; (void)ws_size;
  char* ws = (char*)d_ws;
  Params p;
  p.tids = (const int*)d_in[0];
  p.tlen = (const int*)d_in[1];
  p.lids = (const int*)d_in[2];
  p.llen = (const int*)d_in[3];
  p.rids = (const int*)d_in[4];
  p.rlen = (const int*)d_in[5];
  p.emb  = (const float*)d_in[6];
  p.Wl   = (const float*)d_in[7];
  p.bl   = (const float*)d_in[8];
  p.Wr   = (const float*)d_in[9];
  p.br   = (const float*)d_in[10];
  p.Wd   = (const float*)d_in[11];
  p.bd   = (const float*)d_in[12];
  p.out  = (float*)d_out;
  p.bar  = (int*)ws;                                   // 8 groups x 32 int = 1024 B
  p.hbuf = (unsigned short*)(ws + 1024);               // 2*2*128*512*2 = 524,288 B
  p.hfin = (float*)(ws + 1024 + 524288);               // 2*128*512*4   = 524,288 B
  hipMemsetAsync(ws, 0, 1024, stream);                 // reset flags each launch
  lstm_all<<<dim3(NBLK), dim3(256), 0, stream>>>(p);
}